// Round 5
// baseline (106.144 us; speedup 1.0000x reference)
//
#include <hip/hip_runtime.h>
#include <stdint.h>

#define NN 8192
#define KD 512
#define BM 128
#define BK 32
#define NTILE (NN / BM)                 // 64
#define NTRI (NTILE * (NTILE + 1) / 2)  // 2080
#define NKT (KD / BK)                   // 16

typedef __bf16 bf16;
typedef __bf16 bf16x8 __attribute__((ext_vector_type(8)));
typedef float f32x4 __attribute__((ext_vector_type(4)));

// ---------------- kernel 1: row L2-normalize, fp32 -> bf16 ----------------
__global__ __launch_bounds__(256) void rownorm_kernel(const float* __restrict__ proto,
                                                      bf16* __restrict__ pn) {
    const int row  = blockIdx.x * 4 + (threadIdx.x >> 6);
    const int lane = threadIdx.x & 63;
    const float4* src = (const float4*)(proto + (size_t)row * KD) + lane * 2;
    const float4 v0 = src[0];
    const float4 v1 = src[1];
    float s = v0.x*v0.x + v0.y*v0.y + v0.z*v0.z + v0.w*v0.w
            + v1.x*v1.x + v1.y*v1.y + v1.z*v1.z + v1.w*v1.w;
#pragma unroll
    for (int off = 32; off; off >>= 1) s += __shfl_xor(s, off);
    const float inv = 1.0f / fmaxf(sqrtf(s), 1e-12f);
    bf16x8 o;
    o[0] = (bf16)(v0.x*inv); o[1] = (bf16)(v0.y*inv);
    o[2] = (bf16)(v0.z*inv); o[3] = (bf16)(v0.w*inv);
    o[4] = (bf16)(v1.x*inv); o[5] = (bf16)(v1.y*inv);
    o[6] = (bf16)(v1.z*inv); o[7] = (bf16)(v1.w*inv);
    *(bf16x8*)(pn + (size_t)row * KD + lane * 8) = o;
}

// --- kernel 2: C = leakyrelu(P P^T), symmetric, 4-deep counted pipeline ---
__device__ __forceinline__ void gload_lds16(const bf16* g, bf16* l) {
    __builtin_amdgcn_global_load_lds(
        (const __attribute__((address_space(1))) void*)g,
        (__attribute__((address_space(3))) void*)l, 16, 0, 0);
}

__device__ __forceinline__ float lrelu(float v) {
    return (v >= 0.0f) ? v : 0.01f * v;
}

__global__ __launch_bounds__(256, 2) void gemm_sym_kernel(const bf16* __restrict__ P,
                                                          float* __restrict__ C) {
    // 4-deep ring: [buf][A=0/B=1][128*32 elems] = 64 KB -> 2 blocks/CU
    __shared__ bf16 sm[4][2][128 * 32];

    // bijective XCD swizzle: 2080 = 8 x 260
    const int bid = blockIdx.x;
    const int swz = (bid & 7) * (NTRI / 8) + (bid >> 3);
    int tm = 0, rem = swz;
    while (rem >= NTILE - tm) { rem -= NTILE - tm; ++tm; }
    const int tn = tm + rem;

    const int tid  = threadIdx.x;
    const int w    = tid >> 6;       // wave 0..3 (2x2 grid)
    const int lane = tid & 63;
    const int rowA0 = tm * BM;
    const int rowB0 = tn * BM;
    const int wm = (w >> 1) * 64;
    const int wn = (w & 1) * 64;
    const int rr = lane & 15;
    const int h  = lane >> 4;

    // staging: thread covers LDS bytes [tid*16) and [tid*16+4096) of each
    // 8KB half: row = tid>>2 (+64 for 2nd load), col = (tid&3)*8
    const bf16* gA = P + (size_t)(rowA0 + (tid >> 2)) * KD + (tid & 3) * 8;
    const bf16* gB = P + (size_t)(rowB0 + (tid >> 2)) * KD + (tid & 3) * 8;
    const int stL = w * 512;         // wave-uniform LDS element offset

    // fragment read offsets (elements): row = (wm|wn) + m*16 + rr, col = h*8
    const int aOff = (wm + rr) * 32 + h * 8;
    const int bOff = (wn + rr) * 32 + h * 8;

    f32x4 acc[4][4] = {};

#define VMCNT(n) asm volatile("s_waitcnt vmcnt(" #n ")" ::: "memory")

#define STAGE(tt)                                                         \
    do {                                                                  \
        bf16* a_ = &sm[(tt) & 3][0][0];                                   \
        bf16* b_ = &sm[(tt) & 3][1][0];                                   \
        const int kt_ = (tt) * BK;                                        \
        gload_lds16(gA + kt_,           a_ + stL);                        \
        gload_lds16(gA + 64 * KD + kt_, a_ + stL + 2048);                 \
        gload_lds16(gB + kt_,           b_ + stL);                        \
        gload_lds16(gB + 64 * KD + kt_, b_ + stL + 2048);                 \
    } while (0)

    // phase t: ds_read(tile t) || stage(tile t+3) -> counted vmcnt ->
    //          barrier -> setprio(1) 16xMFMA setprio(0) -> barrier
#define PHASE(t, VMA)                                                     \
    do {                                                                  \
        const bf16* ra_ = &sm[(t) & 3][0][0];                             \
        const bf16* rb_ = &sm[(t) & 3][1][0];                             \
        bf16x8 af[4], bfr[4];                                             \
        _Pragma("unroll") for (int m = 0; m < 4; ++m)                     \
            af[m] = *(const bf16x8*)(ra_ + aOff + m * 512);               \
        _Pragma("unroll") for (int n = 0; n < 4; ++n)                     \
            bfr[n] = *(const bf16x8*)(rb_ + bOff + n * 512);              \
        if ((t) + 3 < NKT) STAGE((t) + 3);                                \
        VMA;                                                              \
        __builtin_amdgcn_s_barrier();                                     \
        __builtin_amdgcn_s_setprio(1);                                    \
        _Pragma("unroll") for (int m = 0; m < 4; ++m)                     \
            _Pragma("unroll") for (int n = 0; n < 4; ++n)                 \
                acc[m][n] = __builtin_amdgcn_mfma_f32_16x16x32_bf16(      \
                    af[m], bfr[n], acc[m][n], 0, 0, 0);                   \
        __builtin_amdgcn_s_setprio(0);                                    \
        __builtin_amdgcn_s_barrier();                                     \
    } while (0)

    // prologue: tiles 0,1,2 in flight; ensure tile 0 landed (2 newest stay)
    STAGE(0); STAGE(1); STAGE(2);
    VMCNT(8);
    __builtin_amdgcn_s_barrier();

    PHASE(0,  VMCNT(8));  PHASE(1,  VMCNT(8));  PHASE(2,  VMCNT(8));
    PHASE(3,  VMCNT(8));  PHASE(4,  VMCNT(8));  PHASE(5,  VMCNT(8));
    PHASE(6,  VMCNT(8));  PHASE(7,  VMCNT(8));  PHASE(8,  VMCNT(8));
    PHASE(9,  VMCNT(8));  PHASE(10, VMCNT(8));  PHASE(11, VMCNT(8));
    PHASE(12, VMCNT(8));  PHASE(13, VMCNT(4));  PHASE(14, VMCNT(0));
    PHASE(15, (void)0);

#undef PHASE
#undef STAGE
#undef VMCNT

    const int cr = h * 4;            // acc reg r -> row cr+r
    const int cc = rr;               // col

    // direct tile: C[rowA0 + ..][rowB0 + ..]
#pragma unroll
    for (int m = 0; m < 4; ++m)
#pragma unroll
        for (int n = 0; n < 4; ++n)
#pragma unroll
            for (int r = 0; r < 4; ++r)
                C[(size_t)(rowA0 + wm + m * 16 + cr + r) * NN
                  + (rowB0 + wn + n * 16 + cc)] = lrelu(acc[m][n][r]);

    // mirror tile (off-diagonal only): per-lane float4 rows of C^T
    if (tm != tn) {
#pragma unroll
        for (int m = 0; m < 4; ++m)
#pragma unroll
            for (int n = 0; n < 4; ++n) {
                float4 vv;
                vv.x = lrelu(acc[m][n][0]);
                vv.y = lrelu(acc[m][n][1]);
                vv.z = lrelu(acc[m][n][2]);
                vv.w = lrelu(acc[m][n][3]);
                *(float4*)&C[(size_t)(rowB0 + wn + n * 16 + cc) * NN
                             + (rowA0 + wm + m * 16 + cr)] = vv;
            }
    }
}

extern "C" void kernel_launch(void* const* d_in, const int* in_sizes, int n_in,
                              void* d_out, int out_size, void* d_ws, size_t ws_size,
                              hipStream_t stream) {
    const float* proto = (const float*)d_in[1];
    float* C  = (float*)d_out;
    bf16* pn  = (bf16*)d_ws;   // 8 MB scratch

    rownorm_kernel<<<dim3(NN / 4), dim3(256), 0, stream>>>(proto, pn);
    gemm_sym_kernel<<<dim3(NTRI), dim3(256), 0, stream>>>(pn, C);
}

// Round 6
// 102.856 us; speedup vs baseline: 1.0320x; 1.0320x over previous
//
#include <hip/hip_runtime.h>
#include <stdint.h>

#define NN 8192
#define KD 512
#define BM 128
#define BK 32
#define NTILE (NN / BM)                 // 64
#define NTRI (NTILE * (NTILE + 1) / 2)  // 2080
#define NKT (KD / BK)                   // 16

typedef __bf16 bf16;
typedef __bf16 bf16x8 __attribute__((ext_vector_type(8)));
typedef float f32x4 __attribute__((ext_vector_type(4)));

// ---------------- kernel 1: row L2-normalize, fp32 -> bf16 ----------------
__global__ __launch_bounds__(256) void rownorm_kernel(const float* __restrict__ proto,
                                                      bf16* __restrict__ pn) {
    const int row  = blockIdx.x * 4 + (threadIdx.x >> 6);
    const int lane = threadIdx.x & 63;
    const float4* src = (const float4*)(proto + (size_t)row * KD) + lane * 2;
    const float4 v0 = src[0];
    const float4 v1 = src[1];
    float s = v0.x*v0.x + v0.y*v0.y + v0.z*v0.z + v0.w*v0.w
            + v1.x*v1.x + v1.y*v1.y + v1.z*v1.z + v1.w*v1.w;
#pragma unroll
    for (int off = 32; off; off >>= 1) s += __shfl_xor(s, off);
    const float inv = 1.0f / fmaxf(sqrtf(s), 1e-12f);
    bf16x8 o;
    o[0] = (bf16)(v0.x*inv); o[1] = (bf16)(v0.y*inv);
    o[2] = (bf16)(v0.z*inv); o[3] = (bf16)(v0.w*inv);
    o[4] = (bf16)(v1.x*inv); o[5] = (bf16)(v1.y*inv);
    o[6] = (bf16)(v1.z*inv); o[7] = (bf16)(v1.w*inv);
    *(bf16x8*)(pn + (size_t)row * KD + lane * 8) = o;
}

// -- kernel 2: C = leakyrelu(P P^T), symmetric, dbuf + T2 XOR swizzle ------
// Swizzle (involution, 16B-chunk granularity): LDS slot (row, c) holds
// global chunk c ^ ((row>>1)&3). Staged via pre-swizzled GLOBAL source
// (LDS dest stays linear, as global_load_lds requires); fragment reads
// apply the same XOR. Rows then spread across all 32 banks at 2-way (free).
__device__ __forceinline__ void gload_lds16(const bf16* g, bf16* l) {
    __builtin_amdgcn_global_load_lds(
        (const __attribute__((address_space(1))) void*)g,
        (__attribute__((address_space(3))) void*)l, 16, 0, 0);
}

__device__ __forceinline__ float lrelu(float v) {
    return (v >= 0.0f) ? v : 0.01f * v;
}

__global__ __launch_bounds__(256, 4) void gemm_sym_kernel(const bf16* __restrict__ P,
                                                          float* __restrict__ C) {
    __shared__ bf16 sA[2][BM * BK];
    __shared__ bf16 sB[2][BM * BK];

    // bijective XCD swizzle: 2080 = 8 x 260
    const int bid = blockIdx.x;
    const int swz = (bid & 7) * (NTRI / 8) + (bid >> 3);
    int tm = 0, rem = swz;
    while (rem >= NTILE - tm) { rem -= NTILE - tm; ++tm; }
    const int tn = tm + rem;

    const int tid  = threadIdx.x;
    const int w    = tid >> 6;
    const int lane = tid & 63;
    const int rowA0 = tm * BM;
    const int rowB0 = tn * BM;
    const int wm = (w >> 1) * 64;
    const int wn = (w & 1) * 64;
    const int rr = lane & 15;
    const int h  = lane >> 4;

    // staging: thread covers LDS bytes tid*16 (rows 0-63) and tid*16+4096
    // (rows 64-127). Global source column pre-swizzled: c ^ ((row>>1)&3).
    // (row+64 leaves (row>>1)&3 unchanged -> same pointer for both loads.)
    const int swcol = ((tid & 3) ^ ((tid >> 3) & 3)) * 8;
    const bf16* gA = P + (size_t)(rowA0 + (tid >> 2)) * KD + swcol;
    const bf16* gB = P + (size_t)(rowB0 + (tid >> 2)) * KD + swcol;
    const int stL = w * 512;   // wave-uniform LDS element offset (HW adds lane*16)

    // fragment reads: want global (row = wm|wn + m*16 + rr, chunk h);
    // swizzled chunk = h ^ ((rr>>1)&3)  (wm/wn/m*16 shift rows by mult. of 8
    // -> swizzle bits unchanged; single offset serves all m)
    const int swf  = (h ^ ((rr >> 1) & 3)) * 8;
    const int aOff = (wm + rr) * 32 + swf;
    const int bOff = (wn + rr) * 32 + swf;

    f32x4 acc[4][4] = {};

#define STAGE(buf, kt)                                              \
    do {                                                            \
        gload_lds16(gA + (kt),           &sA[buf][0] + stL);        \
        gload_lds16(gA + 64 * KD + (kt), &sA[buf][0] + stL + 2048); \
        gload_lds16(gB + (kt),           &sB[buf][0] + stL);        \
        gload_lds16(gB + 64 * KD + (kt), &sB[buf][0] + stL + 2048); \
    } while (0)

#define COMPUTE(buf)                                                        \
    do {                                                                    \
        bf16x8 af[4], bfr[4];                                               \
        _Pragma("unroll")                                                   \
        for (int m = 0; m < 4; ++m)                                         \
            af[m] = *(const bf16x8*)(&sA[buf][0] + aOff + m * 512);         \
        _Pragma("unroll")                                                   \
        for (int n = 0; n < 4; ++n)                                         \
            bfr[n] = *(const bf16x8*)(&sB[buf][0] + bOff + n * 512);        \
        _Pragma("unroll")                                                   \
        for (int m = 0; m < 4; ++m)                                         \
            _Pragma("unroll")                                               \
            for (int n = 0; n < 4; ++n)                                     \
                acc[m][n] = __builtin_amdgcn_mfma_f32_16x16x32_bf16(        \
                    af[m], bfr[n], acc[m][n], 0, 0, 0);                     \
    } while (0)

    // prologue: tile 0 -> buf 0
    STAGE(0, 0);
    __syncthreads();

#pragma unroll
    for (int t = 0; t < NKT; ++t) {
        if (t < NKT - 1) STAGE((t + 1) & 1, (t + 1) * BK);
        COMPUTE(t & 1);
        if (t < NKT - 1) __syncthreads();
    }

    const int cr = h * 4;            // acc reg r -> row cr+r
    const int cc = rr;               // col

    // direct tile: C[rowA0 + ..][rowB0 + ..]
#pragma unroll
    for (int m = 0; m < 4; ++m)
#pragma unroll
        for (int n = 0; n < 4; ++n)
#pragma unroll
            for (int r = 0; r < 4; ++r)
                C[(size_t)(rowA0 + wm + m * 16 + cr + r) * NN
                  + (rowB0 + wn + n * 16 + cc)] = lrelu(acc[m][n][r]);

    // mirror tile (off-diagonal only): per-lane float4 rows of C^T
    if (tm != tn) {
#pragma unroll
        for (int m = 0; m < 4; ++m)
#pragma unroll
            for (int n = 0; n < 4; ++n) {
                float4 vv;
                vv.x = lrelu(acc[m][n][0]);
                vv.y = lrelu(acc[m][n][1]);
                vv.z = lrelu(acc[m][n][2]);
                vv.w = lrelu(acc[m][n][3]);
                *(float4*)&C[(size_t)(rowB0 + wn + n * 16 + cc) * NN
                             + (rowA0 + wm + m * 16 + cr)] = vv;
            }
    }
#undef STAGE
#undef COMPUTE
}

extern "C" void kernel_launch(void* const* d_in, const int* in_sizes, int n_in,
                              void* d_out, int out_size, void* d_ws, size_t ws_size,
                              hipStream_t stream) {
    const float* proto = (const float*)d_in[1];
    float* C  = (float*)d_out;
    bf16* pn  = (bf16*)d_ws;   // 8 MB scratch

    rownorm_kernel<<<dim3(NN / 4), dim3(256), 0, stream>>>(proto, pn);
    gemm_sym_kernel<<<dim3(NTRI), dim3(256), 0, stream>>>(pn, C);
}